// Round 10
// baseline (154.145 us; speedup 1.0000x reference)
//
#include <hip/hip_runtime.h>
#include <stdint.h>

#define NXS 8192
#define HS  1024

typedef __attribute__((ext_vector_type(8))) short short8;
typedef __attribute__((ext_vector_type(4))) float f32x4;

__device__ __forceinline__ float bf2f(uint32_t b) {
    union { uint32_t u; float f; } c; c.u = b << 16; return c.f;
}
__device__ __forceinline__ uint16_t f2bf(float f) {
    union { float f; uint32_t u; } c; c.f = f;
    return (uint16_t)((c.u + 0x7fffu + ((c.u >> 16) & 1u)) >> 16);
}

// Fragment-packed layout for an [N][1024] bf16 matrix M:
//   Mp[((rt*32 + c)*64 + lane)*8 + j] = M[rt*16 + (lane&15)][c*32 + (lane>>4)*8 + j]
// A-frag (rows) and B-frag (cols) of mfma_16x16x32 share this shape.

// ---- K01: merged prep ----
// [0,512):      Z1p packed = tanh(x@W1^T+b1); one block per 16-row tile
// [512,1024):   Bp1 pack: W2 rows   (GEMM1 B)
// [1024,1536):  Bp2 pack: W2 cols   (GEMM2 B)
// [1536,1824):  init out: y = b3, dydx = 0
// [1824,1888):  W1T[16][1024] bf16 (rows 8..15 zero)
__global__ __launch_bounds__(256) void k01(
    const float* __restrict__ x, const float* __restrict__ W1,
    const float* __restrict__ b1, const float* __restrict__ W2,
    const float* __restrict__ b3, uint16_t* __restrict__ Z1p,
    uint16_t* __restrict__ Bp1, uint16_t* __restrict__ Bp2,
    uint16_t* __restrict__ W1T, float* __restrict__ out)
{
    const int b = blockIdx.x, t = threadIdx.x;
    if (b < 512) {
        __shared__ float w1s[8192];      // W1[1024][8]
        __shared__ float b1s[1024];
        __shared__ float xs[16][8];
        const int rt = b;
#pragma unroll
        for (int i = 0; i < 8; ++i)
            *(float4*)&w1s[(i * 256 + t) * 4] = *(const float4*)(W1 + (i * 256 + t) * 4);
#pragma unroll
        for (int i = 0; i < 4; ++i) b1s[i * 256 + t] = b1[i * 256 + t];
        if (t < 128) xs[t >> 3][t & 7] = x[rt * 128 + t];
        __syncthreads();
        const int r = t & 15;
        float xv[8];
#pragma unroll
        for (int k = 0; k < 8; ++k) xv[k] = xs[r][k];
#pragma unroll
        for (int c8 = 0; c8 < 8; ++c8) {
            const int kb = (t >> 4) + c8 * 16;          // [0,128) 8-col chunk
            uint16_t o[8];
#pragma unroll
            for (int j = 0; j < 8; ++j) {
                const int col = kb * 8 + j;
                float s = b1s[col];
#pragma unroll
                for (int k = 0; k < 8; ++k) s += xv[k] * w1s[col * 8 + k];
                o[j] = f2bf(tanhf(s));
            }
            const int c = kb >> 2, lq = kb & 3;
            uint16_t* dst = Z1p + ((size_t)(rt * 32 + c) * 64 + lq * 16 + r) * 8;
            *(ushort4*)dst       = *(ushort4*)&o[0];
            *(ushort4*)(dst + 4) = *(ushort4*)&o[4];
        }
    } else if (b < 1024) {
        const int tid = (b - 512) * 256 + t;             // 0..131071
        const int l = tid & 63, c = (tid >> 6) & 31, g = tid >> 11;
        const int lr = l & 15, lq = l >> 4;
        const float* src = W2 + (size_t)(g * 16 + lr) * HS + c * 32 + lq * 8;
        float4 a0 = *(const float4*)src;
        float4 a1 = *(const float4*)(src + 4);
        uint16_t o[8];
        o[0] = f2bf(a0.x); o[1] = f2bf(a0.y); o[2] = f2bf(a0.z); o[3] = f2bf(a0.w);
        o[4] = f2bf(a1.x); o[5] = f2bf(a1.y); o[6] = f2bf(a1.z); o[7] = f2bf(a1.w);
        *(ushort4*)(Bp1 + (size_t)tid * 8)     = *(ushort4*)&o[0];
        *(ushort4*)(Bp1 + (size_t)tid * 8 + 4) = *(ushort4*)&o[4];
    } else if (b < 1536) {
        const int tid = (b - 1024) * 256 + t;
        const int l = tid & 63, c = (tid >> 6) & 31, g = tid >> 11;
        const int lr = l & 15, lq = l >> 4;
        uint16_t o[8];
#pragma unroll
        for (int j2 = 0; j2 < 8; ++j2)
            o[j2] = f2bf(W2[(size_t)(c * 32 + lq * 8 + j2) * HS + g * 16 + lr]);
        *(ushort4*)(Bp2 + (size_t)tid * 8)     = *(ushort4*)&o[0];
        *(ushort4*)(Bp2 + (size_t)tid * 8 + 4) = *(ushort4*)&o[4];
    } else if (b < 1824) {
        const int idx = (b - 1536) * 256 + t;            // 0..73727
        out[idx] = (idx < NXS) ? b3[0] : 0.f;
    } else {
        const int idx = (b - 1824) * 256 + t;            // 0..16383
        const int r = idx >> 10, cc = idx & 1023;
        W1T[idx] = (r < 8) ? f2bf(W1[cc * 8 + r]) : (uint16_t)0;
    }
}

// -------- GEMM: 64x128 tile, 4 waves, fully barrier-free K-loop --------
// Both operands fragment-packed in global; K-loop = dwordx4 loads + MFMA only.
// Wave w owns rows[0,64) x cols[w*32,+32): acc[4][2].
// MODE 0: C = Z1 @ W2^T (Bp1); epilogue tanh -> y atomics + packed-V via LDS
// MODE 1: C = U = V @ W2 (Bp2); fused MFMA dydx epilogue via W1T
template <int MODE>
__global__ __launch_bounds__(256, 4) void gemm_k(
    const uint16_t* __restrict__ Ap, const uint16_t* __restrict__ Bp,
    const float* __restrict__ bias, const float* __restrict__ W3,
    uint16_t* __restrict__ Vp, float* __restrict__ yOut,
    const uint16_t* __restrict__ Z1p, const uint16_t* __restrict__ W1T,
    float* __restrict__ dOut)
{
    __shared__ __attribute__((aligned(16))) uint16_t smem[64 * 136]; // epilogue only
    const int t = threadIdx.x;
    const int wave = t >> 6, lane = t & 63;
    const int lq = lane >> 4, lr = lane & 15;
    const int rowBase = blockIdx.x * 64;
    const int colBase = blockIdx.y * 128;

    // A frags: rt0 = rowBase/16 (+ti); B frags: g0 = colBase/16 + wave*2 (+1)
    const uint16_t* pA  = Ap + ((size_t)(rowBase >> 4) * 32) * 512 + (size_t)lane * 8;
    const uint16_t* pB0 = Bp + ((size_t)(colBase >> 4) + wave * 2) * 16384 + (size_t)lane * 8;
    const uint16_t* pB1 = pB0 + 16384;

    f32x4 acc[4][2] = {};

    short8 ac[4], b0c, b1c;
#pragma unroll
    for (int ti = 0; ti < 4; ++ti)
        ac[ti] = *(const short8*)(pA + (size_t)ti * 16384);
    b0c = *(const short8*)pB0;
    b1c = *(const short8*)pB1;

    for (int c = 0; c < 32; ++c) {
        short8 an[4] = {ac[0], ac[1], ac[2], ac[3]};
        short8 b0n = b0c, b1n = b1c;
        if (c < 31) {
            const size_t off = (size_t)(c + 1) * 512;
#pragma unroll
            for (int ti = 0; ti < 4; ++ti)
                an[ti] = *(const short8*)(pA + (size_t)ti * 16384 + off);
            b0n = *(const short8*)(pB0 + off);
            b1n = *(const short8*)(pB1 + off);
        }
#pragma unroll
        for (int ti = 0; ti < 4; ++ti) {
            acc[ti][0] = __builtin_amdgcn_mfma_f32_16x16x32_bf16(ac[ti], b0c, acc[ti][0], 0, 0, 0);
            acc[ti][1] = __builtin_amdgcn_mfma_f32_16x16x32_bf16(ac[ti], b1c, acc[ti][1], 0, 0, 0);
        }
#pragma unroll
        for (int ti = 0; ti < 4; ++ti) ac[ti] = an[ti];
        b0c = b0n; b1c = b1n;
    }

    if (MODE == 0) {
        float cB[2], cW[2]; int cCol[2];
#pragma unroll
        for (int tj = 0; tj < 2; ++tj) {
            cCol[tj] = wave * 32 + tj * 16 + lr;            // col-local
            cB[tj] = bias[colBase + cCol[tj]];
            cW[tj] = W3[colBase + cCol[tj]];
        }
#pragma unroll
        for (int ti = 0; ti < 4; ++ti) {
#pragma unroll
            for (int r = 0; r < 4; ++r) {
                int rowl = ti * 16 + lq * 4 + r;
                float ys = 0.f;
#pragma unroll
                for (int tj = 0; tj < 2; ++tj) {
                    float z2 = tanhf(acc[ti][tj][r] + cB[tj]);
                    ys += z2 * cW[tj];
                    smem[rowl * 136 + cCol[tj]] = f2bf((1.f - z2 * z2) * cW[tj]);
                }
                ys += __shfl_xor(ys, 1); ys += __shfl_xor(ys, 2);
                ys += __shfl_xor(ys, 4); ys += __shfl_xor(ys, 8);
                if (lr == 0) atomicAdd(&yOut[rowBase + rowl], ys);
            }
        }
        __syncthreads();
        // LDS [64][128] -> packed V: 1024 short8s, coalesced
#pragma unroll
        for (int i = 0; i < 4; ++i) {
            const int s = i * 256 + t;
            const int rl = s >> 4, kc = s & 15;
            short8 v = *(const short8*)(smem + rl * 136 + kc * 8);
            const int rt = (rowBase >> 4) + (rl >> 4);
            const int c2 = (colBase >> 5) + (kc >> 2);
            *(short8*)(Vp + ((size_t)(rt * 32 + c2) * 64 + (kc & 3) * 16 + (rl & 15)) * 8) = v;
        }
    } else {
        // c = U*(1-z1^2) -> LDS rows [64][stride 136]
#pragma unroll
        for (int ti = 0; ti < 4; ++ti)
#pragma unroll
            for (int r = 0; r < 4; ++r) {
                const int rowl = ti * 16 + lq * 4 + r;
                const int rt_z = (rowBase >> 4) + ti;
                const int lrp = lq * 4 + r;
#pragma unroll
                for (int tj = 0; tj < 2; ++tj) {
                    const int col = colBase + wave * 32 + tj * 16 + lr;
                    const int cz = col >> 5, lqz = (col >> 3) & 3, jz = col & 7;
                    float z1 = bf2f(Z1p[((size_t)(rt_z * 32 + cz) * 64 + lqz * 16 + lrp) * 8 + jz]);
                    smem[rowl * 136 + wave * 32 + tj * 16 + lr] =
                        f2bf(acc[ti][tj][r] * (1.f - z1 * z1));
                }
            }
        __syncthreads();
        // D[16x8 per wave] = c-rows [wave*16,+16) @ W1T-slice, via 4 MFMAs
        f32x4 dd = {};
#pragma unroll
        for (int kb = 0; kb < 4; ++kb) {
            short8 aF = *(const short8*)(smem + (wave * 16 + lr) * 136 + kb * 32 + lq * 8);
            short8 bF = *(const short8*)(W1T + lr * HS + colBase + kb * 32 + lq * 8);
            dd = __builtin_amdgcn_mfma_f32_16x16x32_bf16(aF, bF, dd, 0, 0, 0);
        }
        if (lr < 8) {
            const int row = rowBase + wave * 16 + lq * 4;
#pragma unroll
            for (int rg = 0; rg < 4; ++rg)
                atomicAdd(&dOut[(size_t)lr * NXS + row + rg], dd[rg]);
        }
    }
}

extern "C" void kernel_launch(void* const* d_in, const int* in_sizes, int n_in,
                              void* d_out, int out_size, void* d_ws, size_t ws_size,
                              hipStream_t stream) {
    (void)in_sizes; (void)n_in; (void)out_size; (void)ws_size;
    const float* x  = (const float*)d_in[0];
    const float* W1 = (const float*)d_in[1];
    const float* b1 = (const float*)d_in[2];
    const float* W2 = (const float*)d_in[3];
    const float* b2 = (const float*)d_in[4];
    const float* W3 = (const float*)d_in[5];
    const float* b3 = (const float*)d_in[6];
    float* out = (float*)d_out;

    char* ws = (char*)d_ws;
    // ws layout:
    //   [0, 16MB)     Z1p bf16 fragment-packed (live through GEMM2 epilogue)
    //   [16MB, 32MB)  Vp  bf16 fragment-packed
    //   [32MB, 34MB)  Bp1 bf16 fragment-packed W2    (GEMM1 B)
    //   [34MB, 36MB)  Bp2 bf16 fragment-packed W2^T  (GEMM2 B)
    //   [36MB, +32KB) W1T bf16 [16][1024] (rows 8..15 zero)
    uint16_t* Z1p = (uint16_t*)(ws);
    uint16_t* Vp  = (uint16_t*)(ws + (size_t)16 * 1024 * 1024);
    uint16_t* Bp1 = (uint16_t*)(ws + (size_t)32 * 1024 * 1024);
    uint16_t* Bp2 = (uint16_t*)(ws + (size_t)34 * 1024 * 1024);
    uint16_t* W1T = (uint16_t*)(ws + (size_t)36 * 1024 * 1024);

    k01<<<1888, 256, 0, stream>>>(x, W1, b1, W2, b3, Z1p, Bp1, Bp2, W1T, out);
    gemm_k<0><<<dim3(NXS / 64, HS / 128), 256, 0, stream>>>(
        Z1p, Bp1, b2, W3, Vp, out, nullptr, nullptr, nullptr);
    gemm_k<1><<<dim3(NXS / 64, HS / 128), 256, 0, stream>>>(
        Vp, Bp2, nullptr, nullptr, nullptr, nullptr, Z1p, W1T, out + NXS);
}

// Round 13
// 137.028 us; speedup vs baseline: 1.1249x; 1.1249x over previous
//
#include <hip/hip_runtime.h>
#include <stdint.h>

#define NXS 8192
#define HS  1024

typedef __attribute__((ext_vector_type(8))) short short8;
typedef __attribute__((ext_vector_type(4))) float f32x4;

__device__ __forceinline__ float bf2f(uint32_t b) {
    union { uint32_t u; float f; } c; c.u = b << 16; return c.f;
}
__device__ __forceinline__ uint16_t f2bf(float f) {
    union { float f; uint32_t u; } c; c.f = f;
    return (uint16_t)((c.u + 0x7fffu + ((c.u >> 16) & 1u)) >> 16);
}
__device__ __forceinline__ void async_cp16(const void* g, void* l) {
    __builtin_amdgcn_global_load_lds(
        (const __attribute__((address_space(1))) void*)g,
        (__attribute__((address_space(3))) void*)l,
        16, 0, 0);
}

// Fragment-packed layout for an [N][1024] bf16 matrix M:
//   Mp[((rt*32 + c)*64 + lane)*8 + j] = M[rt*16 + (lane&15)][c*32 + (lane>>4)*8 + j]

// ---- K01: merged prep (identical to R10) ----
__global__ __launch_bounds__(256) void k01(
    const float* __restrict__ x, const float* __restrict__ W1,
    const float* __restrict__ b1, const float* __restrict__ W2,
    const float* __restrict__ b3, uint16_t* __restrict__ Z1p,
    uint16_t* __restrict__ Bp1, uint16_t* __restrict__ Bp2,
    uint16_t* __restrict__ W1T, float* __restrict__ out)
{
    const int b = blockIdx.x, t = threadIdx.x;
    if (b < 512) {
        __shared__ float w1s[8192];      // W1[1024][8]
        __shared__ float b1s[1024];
        __shared__ float xs[16][8];
        const int rt = b;
#pragma unroll
        for (int i = 0; i < 8; ++i)
            *(float4*)&w1s[(i * 256 + t) * 4] = *(const float4*)(W1 + (i * 256 + t) * 4);
#pragma unroll
        for (int i = 0; i < 4; ++i) b1s[i * 256 + t] = b1[i * 256 + t];
        if (t < 128) xs[t >> 3][t & 7] = x[rt * 128 + t];
        __syncthreads();
        const int r = t & 15;
        float xv[8];
#pragma unroll
        for (int k = 0; k < 8; ++k) xv[k] = xs[r][k];
#pragma unroll
        for (int c8 = 0; c8 < 8; ++c8) {
            const int kb = (t >> 4) + c8 * 16;
            uint16_t o[8];
#pragma unroll
            for (int j = 0; j < 8; ++j) {
                const int col = kb * 8 + j;
                float s = b1s[col];
#pragma unroll
                for (int k = 0; k < 8; ++k) s += xv[k] * w1s[col * 8 + k];
                o[j] = f2bf(tanhf(s));
            }
            const int c = kb >> 2, lq = kb & 3;
            uint16_t* dst = Z1p + ((size_t)(rt * 32 + c) * 64 + lq * 16 + r) * 8;
            *(ushort4*)dst       = *(ushort4*)&o[0];
            *(ushort4*)(dst + 4) = *(ushort4*)&o[4];
        }
    } else if (b < 1024) {
        const int tid = (b - 512) * 256 + t;
        const int l = tid & 63, c = (tid >> 6) & 31, g = tid >> 11;
        const int lr = l & 15, lq = l >> 4;
        const float* src = W2 + (size_t)(g * 16 + lr) * HS + c * 32 + lq * 8;
        float4 a0 = *(const float4*)src;
        float4 a1 = *(const float4*)(src + 4);
        uint16_t o[8];
        o[0] = f2bf(a0.x); o[1] = f2bf(a0.y); o[2] = f2bf(a0.z); o[3] = f2bf(a0.w);
        o[4] = f2bf(a1.x); o[5] = f2bf(a1.y); o[6] = f2bf(a1.z); o[7] = f2bf(a1.w);
        *(ushort4*)(Bp1 + (size_t)tid * 8)     = *(ushort4*)&o[0];
        *(ushort4*)(Bp1 + (size_t)tid * 8 + 4) = *(ushort4*)&o[4];
    } else if (b < 1536) {
        const int tid = (b - 1024) * 256 + t;
        const int l = tid & 63, c = (tid >> 6) & 31, g = tid >> 11;
        const int lr = l & 15, lq = l >> 4;
        uint16_t o[8];
#pragma unroll
        for (int j2 = 0; j2 < 8; ++j2)
            o[j2] = f2bf(W2[(size_t)(c * 32 + lq * 8 + j2) * HS + g * 16 + lr]);
        *(ushort4*)(Bp2 + (size_t)tid * 8)     = *(ushort4*)&o[0];
        *(ushort4*)(Bp2 + (size_t)tid * 8 + 4) = *(ushort4*)&o[4];
    } else if (b < 1824) {
        const int idx = (b - 1536) * 256 + t;
        out[idx] = (idx < NXS) ? b3[0] : 0.f;
    } else {
        const int idx = (b - 1824) * 256 + t;
        const int r = idx >> 10, cc = idx & 1023;
        W1T[idx] = (r < 8) ? f2bf(W1[cc * 8 + r]) : (uint16_t)0;
    }
}

// ---- GEMM: 64x128 tile, 4 waves, BK=64, triple-buffered A staging, B direct ----
// One __syncthreads per 64-K step (16 drains total; R9 had 32).
// Triple-buffer: epoch(it+1) writes buf (it+2)%3, epoch(it) reads buf it%3 -- disjoint.
// MODE 0: C = Z1 @ W2^T (Bp1); epilogue tanh -> y atomics + packed-V via LDS
// MODE 1: C = U = V @ W2 (Bp2); fused MFMA dydx epilogue via W1T
template <int MODE>
__global__ __launch_bounds__(256, 4) void gemm_k(
    const uint16_t* __restrict__ Ap, const uint16_t* __restrict__ Bp,
    const float* __restrict__ bias, const float* __restrict__ W3,
    uint16_t* __restrict__ Vp, float* __restrict__ yOut,
    const uint16_t* __restrict__ Z1p, const uint16_t* __restrict__ W1T,
    float* __restrict__ dOut)
{
    // 24 KB: 3 A-buffers of 8192 B; epilogue reuses [0, 17408)
    __shared__ __attribute__((aligned(16))) uint16_t smem[12288];
    const int t = threadIdx.x;
    const int wave = t >> 6, lane = t & 63;
    const int lq = lane >> 4, lr = lane & 15;
    const int rowBase = blockIdx.x * 64;
    const int colBase = blockIdx.y * 128;

    // A staging (packed): 512 segs/iter = (ti 0..3) x (cp 0..1) x (lane 0..63).
    // Thread t handles seg t (ti=t>>7, cp=(t>>6)&1) and seg 256+t (ti+2).
    const int ti0 = t >> 7, cp = (t >> 6) & 1, ln = t & 63;
    const uint16_t* gA0 = Ap + (((size_t)(rowBase >> 4) + ti0) * 32 + cp) * 512 + (size_t)ln * 8;
    const uint16_t* gA1 = Ap + (((size_t)(rowBase >> 4) + ti0 + 2) * 32 + cp) * 512 + (size_t)ln * 8;
    const uint16_t* pB0 = Bp + ((size_t)(colBase >> 4) + wave * 2) * 16384 + (size_t)lane * 8;
    const uint16_t* pB1 = pB0 + 16384;

    f32x4 acc[4][2] = {};

    // prologue: stage it=0 into buf 0; load B frags for it=0 (c = 0,1)
    async_cp16(gA0, (char*)smem + t * 16);
    async_cp16(gA1, (char*)smem + 4096 + t * 16);
    short8 bc00 = *(const short8*)pB0;           // kk=0, tj=0
    short8 bc01 = *(const short8*)pB1;           // kk=0, tj=1
    short8 bc10 = *(const short8*)(pB0 + 512);   // kk=1, tj=0
    short8 bc11 = *(const short8*)(pB1 + 512);

    int buf = 0;
    for (int it = 0; it < 16; ++it) {
        short8 bn00 = bc00, bn01 = bc01, bn10 = bc10, bn11 = bc11;
        const int nb = (buf == 2) ? 0 : buf + 1;
        if (it < 15) {
            const size_t aoff = (size_t)(it + 1) * 1024;
            async_cp16(gA0 + aoff, (char*)smem + nb * 8192 + t * 16);
            async_cp16(gA1 + aoff, (char*)smem + nb * 8192 + 4096 + t * 16);
            const size_t boff = (size_t)(2 * it + 2) * 512;
            bn00 = *(const short8*)(pB0 + boff);
            bn01 = *(const short8*)(pB1 + boff);
            bn10 = *(const short8*)(pB0 + boff + 512);
            bn11 = *(const short8*)(pB1 + boff + 512);
        }
        __syncthreads();   // drains all VMEM (current A landed) + wave sync
        const short* pA = (const short*)smem + buf * 4096;
#pragma unroll
        for (int kk = 0; kk < 2; ++kk) {
            short8 af[4];
#pragma unroll
            for (int ti = 0; ti < 4; ++ti)
                af[ti] = *(const short8*)(pA + ti * 1024 + kk * 512 + lane * 8);
            const short8 b0 = kk ? bc10 : bc00;
            const short8 b1 = kk ? bc11 : bc01;
#pragma unroll
            for (int ti = 0; ti < 4; ++ti) {
                acc[ti][0] = __builtin_amdgcn_mfma_f32_16x16x32_bf16(af[ti], b0, acc[ti][0], 0, 0, 0);
                acc[ti][1] = __builtin_amdgcn_mfma_f32_16x16x32_bf16(af[ti], b1, acc[ti][1], 0, 0, 0);
            }
        }
        bc00 = bn00; bc01 = bn01; bc10 = bn10; bc11 = bn11;
        buf = nb;
    }
    __syncthreads();   // all K-loop LDS reads done before epilogue reuses smem

    if (MODE == 0) {
        float cB[2], cW[2]; int cCol[2];
#pragma unroll
        for (int tj = 0; tj < 2; ++tj) {
            cCol[tj] = wave * 32 + tj * 16 + lr;            // col-local
            cB[tj] = bias[colBase + cCol[tj]];
            cW[tj] = W3[colBase + cCol[tj]];
        }
#pragma unroll
        for (int ti = 0; ti < 4; ++ti) {
#pragma unroll
            for (int r = 0; r < 4; ++r) {
                int rowl = ti * 16 + lq * 4 + r;
                float ys = 0.f;
#pragma unroll
                for (int tj = 0; tj < 2; ++tj) {
                    float z2 = tanhf(acc[ti][tj][r] + cB[tj]);
                    ys += z2 * cW[tj];
                    smem[rowl * 136 + cCol[tj]] = f2bf((1.f - z2 * z2) * cW[tj]);
                }
                ys += __shfl_xor(ys, 1); ys += __shfl_xor(ys, 2);
                ys += __shfl_xor(ys, 4); ys += __shfl_xor(ys, 8);
                if (lr == 0) atomicAdd(&yOut[rowBase + rowl], ys);
            }
        }
        __syncthreads();
        // LDS [64][128] -> packed V: 1024 short8s, coalesced
#pragma unroll
        for (int i = 0; i < 4; ++i) {
            const int s = i * 256 + t;
            const int rl = s >> 4, kc = s & 15;
            short8 v = *(const short8*)(smem + rl * 136 + kc * 8);
            const int rt = (rowBase >> 4) + (rl >> 4);
            const int c2 = (colBase >> 5) + (kc >> 2);
            *(short8*)(Vp + ((size_t)(rt * 32 + c2) * 64 + (kc & 3) * 16 + (rl & 15)) * 8) = v;
        }
    } else {
        // c = U*(1-z1^2) -> LDS rows [64][stride 136]
#pragma unroll
        for (int ti = 0; ti < 4; ++ti)
#pragma unroll
            for (int r = 0; r < 4; ++r) {
                const int rowl = ti * 16 + lq * 4 + r;
                const int rt_z = (rowBase >> 4) + ti;
                const int lrp = lq * 4 + r;
#pragma unroll
                for (int tj = 0; tj < 2; ++tj) {
                    const int col = colBase + wave * 32 + tj * 16 + lr;
                    const int cz = col >> 5, lqz = (col >> 3) & 3, jz = col & 7;
                    float z1 = bf2f(Z1p[((size_t)(rt_z * 32 + cz) * 64 + lqz * 16 + lrp) * 8 + jz]);
                    smem[rowl * 136 + wave * 32 + tj * 16 + lr] =
                        f2bf(acc[ti][tj][r] * (1.f - z1 * z1));
                }
            }
        __syncthreads();
        // D[16x8 per wave] = c-rows [wave*16,+16) @ W1T-slice, via 4 MFMAs
        f32x4 dd = {};
#pragma unroll
        for (int kb = 0; kb < 4; ++kb) {
            short8 aF = *(const short8*)(smem + (wave * 16 + lr) * 136 + kb * 32 + lq * 8);
            short8 bF = *(const short8*)(W1T + lr * HS + colBase + kb * 32 + lq * 8);
            dd = __builtin_amdgcn_mfma_f32_16x16x32_bf16(aF, bF, dd, 0, 0, 0);
        }
        if (lr < 8) {
            const int row = rowBase + wave * 16 + lq * 4;
#pragma unroll
            for (int rg = 0; rg < 4; ++rg)
                atomicAdd(&dOut[(size_t)lr * NXS + row + rg], dd[rg]);
        }
    }
}

extern "C" void kernel_launch(void* const* d_in, const int* in_sizes, int n_in,
                              void* d_out, int out_size, void* d_ws, size_t ws_size,
                              hipStream_t stream) {
    (void)in_sizes; (void)n_in; (void)out_size; (void)ws_size;
    const float* x  = (const float*)d_in[0];
    const float* W1 = (const float*)d_in[1];
    const float* b1 = (const float*)d_in[2];
    const float* W2 = (const float*)d_in[3];
    const float* b2 = (const float*)d_in[4];
    const float* W3 = (const float*)d_in[5];
    const float* b3 = (const float*)d_in[6];
    float* out = (float*)d_out;

    char* ws = (char*)d_ws;
    // ws layout:
    //   [0, 16MB)     Z1p bf16 fragment-packed (live through GEMM2 epilogue)
    //   [16MB, 32MB)  Vp  bf16 fragment-packed
    //   [32MB, 34MB)  Bp1 bf16 fragment-packed W2    (GEMM1 B)
    //   [34MB, 36MB)  Bp2 bf16 fragment-packed W2^T  (GEMM2 B)
    //   [36MB, +32KB) W1T bf16 [16][1024] (rows 8..15 zero)
    uint16_t* Z1p = (uint16_t*)(ws);
    uint16_t* Vp  = (uint16_t*)(ws + (size_t)16 * 1024 * 1024);
    uint16_t* Bp1 = (uint16_t*)(ws + (size_t)32 * 1024 * 1024);
    uint16_t* Bp2 = (uint16_t*)(ws + (size_t)34 * 1024 * 1024);
    uint16_t* W1T = (uint16_t*)(ws + (size_t)36 * 1024 * 1024);

    k01<<<1888, 256, 0, stream>>>(x, W1, b1, W2, b3, Z1p, Bp1, Bp2, W1T, out);
    gemm_k<0><<<dim3(NXS / 64, HS / 128), 256, 0, stream>>>(
        Z1p, Bp1, b2, W3, Vp, out, nullptr, nullptr, nullptr);
    gemm_k<1><<<dim3(NXS / 64, HS / 128), 256, 0, stream>>>(
        Vp, Bp2, nullptr, nullptr, nullptr, nullptr, Z1p, W1T, out + NXS);
}